// Round 7
// baseline (124.747 us; speedup 1.0000x reference)
//
#include <hip/hip_runtime.h>
#include <cstdint>

#define BB 16
#define NN 25200
#define NCLS 80
#define NF (5 + NCLS)
#define MAXDET 300
#define MTGT 50
#define CONF 0.8f
#define NMSTH 0.4f
#define WORDS 10
#define NBINS 2048
#define SBUF 2048
#define APB 64                              // anchors per chunk in k_score
#define NCHUNK ((BB * NN) / APB)            // 6300
#define PBLK 768                            // persistent blocks (3/CU x 256 CU)
#define TGT_BLOCKS ((BB * MTGT + 255) / 256)
#define CHUNK_V4 (APB * NF / 4)             // 1360 float4 per chunk

// workspace byte offsets
#define WS_SCORE 0
#define WS_DS   ((size_t)BB * NN * 4)
#define WS_DI   (WS_DS + (size_t)BB * MAXDET * 4)
#define WS_GBOX (WS_DI + (size_t)BB * MAXDET * 4)
#define WS_GLAB (WS_GBOX + (size_t)BB * MAXDET * 16)

// output float offsets (return order: pb, ps, pl, pv, tb, ts, tl, tv)
#define O_PB 0
#define O_PS (BB * MAXDET * 4)
#define O_PL (O_PS + BB * MAXDET)
#define O_PV (O_PL + BB * MAXDET)
#define O_TB (O_PV + BB * MAXDET)
#define O_TS (O_TB + BB * MTGT * 4)
#define O_TL (O_TS + BB * MTGT)
#define O_TV (O_TL + BB * MTGT)

// Persistent double-buffered scorer: 768 co-resident blocks, each grid-strides
// ~8 chunks of 64 rows. Per chunk: issue next-chunk loads -> scan current buffer
// -> write regs to other buffer -> ONE barrier. HBM latency hides under scan.
// Blocks 0..3 also do the (tiny) target transform first. Max is order-independent
// -> bit-exact; score = single f32 mul.
__global__ __launch_bounds__(256) void k_score(const float* __restrict__ preds,
                                               float* __restrict__ scores,
                                               const float* __restrict__ tt,
                                               const int* __restrict__ len,
                                               float* __restrict__ out) {
    __shared__ float st[2][APB * NF];       // 2 x 21760 B
    int tid = threadIdx.x;
    int bid = blockIdx.x;

    if (bid < TGT_BLOCKS) {                 // fused target transform
        int t = bid * 256 + tid;
        if (t < BB * MTGT) {
            int b = t / MTGT, m = t - b * MTGT;
            const float* row = tt + (size_t)t * 6;
            bool valid = m < len[b];
            float cx = row[0], cy = row[1], w = row[2], h = row[3];
            float x1 = cx - 0.5f * w, y1 = cy - 0.5f * h;
            float* tb = out + O_TB + (size_t)t * 4;
            tb[0] = valid ? x1 : 0.f;
            tb[1] = valid ? y1 : 0.f;
            tb[2] = valid ? (x1 + w) : 0.f;
            tb[3] = valid ? (y1 + h) : 0.f;
            out[O_TS + t] = valid ? row[4] : 0.f;
            out[O_TL + t] = valid ? (float)(int)row[5] : -1.f;
            out[O_TV + t] = valid ? 1.f : 0.f;
        }
    }

    int c = bid;
    float4 r[6];

    // prologue: chunk c -> regs -> buf0 (chunk base byte = c*21760, 16B-aligned)
    {
        const float4* src = (const float4*)(preds + (size_t)c * (APB * NF));
        #pragma unroll
        for (int i = 0; i < 6; ++i) {
            int idx = i * 256 + tid;
            if (idx < CHUNK_V4) r[i] = src[idx];
        }
        #pragma unroll
        for (int i = 0; i < 6; ++i) {
            int idx = i * 256 + tid;
            if (idx < CHUNK_V4) ((float4*)st[0])[idx] = r[i];
        }
    }
    __syncthreads();

    int cur = 0;
    while (true) {
        int nc = c + PBLK;
        bool have_next = nc < NCHUNK;
        if (have_next) {                    // issue next chunk's loads EARLY
            const float4* src = (const float4*)(preds + (size_t)nc * (APB * NF));
            #pragma unroll
            for (int i = 0; i < 6; ++i) {
                int idx = i * 256 + tid;
                if (idx < CHUNK_V4) r[i] = src[idx];
            }
        }

        // scan chunk c from st[cur]: 4 threads/anchor, 20 classes each + 2 hops
        {
            int a = tid >> 2, q = tid & 3;
            const float* row = st[cur] + a * NF;
            const float* cls = row + 5 + q * 20;
            float m = cls[0];
            #pragma unroll
            for (int f = 1; f < 20; ++f) m = fmaxf(m, cls[f]);
            m = fmaxf(m, __shfl_xor(m, 1));
            m = fmaxf(m, __shfl_xor(m, 2));
            if (q == 0) scores[c * APB + a] = row[4] * m;
        }

        if (!have_next) break;
        #pragma unroll
        for (int i = 0; i < 6; ++i) {       // regs -> other buffer (waits vmcnt here)
            int idx = i * 256 + tid;
            if (idx < CHUNK_V4) ((float4*)st[cur ^ 1])[idx] = r[i];
        }
        __syncthreads();                    // one barrier per chunk
        cur ^= 1; c = nc;
    }
}

// one block per batch: histogram top-k selection + small exact bitonic sort.
// Coarse bins only SELECT (all cut-bin ties included); the 64-bit key sort ORDERS,
// so output is bit-identical to a full sort (JAX top_k tie semantics preserved).
__global__ __launch_bounds__(1024) void k_select(const float* __restrict__ scores,
                                                 float* __restrict__ dscore,
                                                 unsigned* __restrict__ didx) {
    __shared__ int hist[NBINS];
    __shared__ unsigned long long sk[SBUF];
    __shared__ int lcnt;
    __shared__ int scut;
    int b = blockIdx.x;
    int tid = threadIdx.x;
    int lane = tid & 63;

    if (tid == 0) lcnt = 0;
    for (int i = tid; i < NBINS; i += 1024) hist[i] = 0;
    for (int i = tid; i < SBUF; i += 1024) sk[i] = 0ull;
    __syncthreads();

    // phase A: histogram of candidate score bits. scores in (0.8,1.0] share one
    // exponent region -> (u - 0x3F400000)>>12 is monotone in float order.
    for (int i = tid; i < NN; i += 1024) {
        float s = scores[b * NN + i];
        if (s > CONF) {
            unsigned u = __float_as_uint(s);
            int bin = (int)((u - 0x3F400000u) >> 12);
            bin = bin < 0 ? 0 : (bin > NBINS - 1 ? NBINS - 1 : bin);
            atomicAdd(&hist[bin], 1);
        }
    }
    __syncthreads();

    // phase B: find cut bin (largest bin with suffix-count >= 300), one wave
    if (tid < 64) {
        int sb = 0;
        #pragma unroll
        for (int k = 0; k < 32; ++k) sb += hist[tid * 32 + k];
        int cum = sb;                              // suffix sum over 64 superbins
        #pragma unroll
        for (int d = 1; d < 64; d <<= 1) {
            int o = __shfl_down(cum, d);
            if (lane + d < 64) cum += o;
        }
        unsigned long long m = __ballot(cum >= MAXDET);
        int cutbin = 0;
        if (m) {
            int cutS = 63 - __clzll(m);
            int tail = (cutS < 63) ? __shfl(cum, cutS + 1) : 0;
            int hh = (lane < 32) ? hist[cutS * 32 + lane] : 0;
            int c2 = hh;                           // suffix sum within superbin
            #pragma unroll
            for (int d = 1; d < 32; d <<= 1) {
                int o = __shfl_down(c2, d);
                if (lane + d < 32) c2 += o;
            }
            c2 += tail;
            unsigned long long m2 = __ballot(lane < 32 && c2 >= MAXDET);
            int cutL = 63 - __clzll(m2);           // m2 != 0 guaranteed
            cutbin = cutS * 32 + cutL;
        }
        if (lane == 0) scut = cutbin;
    }
    __syncthreads();
    int cutbin = scut;

    // phase C: compact bin >= cutbin (wave-aggregated LDS atomic)
    for (int i = tid; i < ((NN + 1023) & ~1023); i += 1024) {
        float s = 0.f; bool pass = false;
        if (i < NN) {
            s = scores[b * NN + i];
            if (s > CONF) {
                unsigned u = __float_as_uint(s);
                int bin = (int)((u - 0x3F400000u) >> 12);
                bin = bin < 0 ? 0 : (bin > NBINS - 1 ? NBINS - 1 : bin);
                pass = bin >= cutbin;
            }
        }
        unsigned long long mask = __ballot(pass);
        int wcnt = __popcll(mask);
        int bs = 0;
        if (lane == 0 && wcnt) bs = atomicAdd(&lcnt, wcnt);
        bs = __shfl(bs, 0);
        if (pass) {
            int pos = bs + __popcll(mask & ((1ull << lane) - 1ull));
            if (pos < SBUF)
                sk[pos] = ((unsigned long long)__float_as_uint(s) << 32) |
                          (unsigned long long)(0xFFFFFFFFu - (unsigned)i);
        }
    }
    __syncthreads();

    // phase D: bitonic sort P in {512,1024,2048} elements, descending
    int M = lcnt; if (M > SBUF) M = SBUF;
    unsigned P = 512;
    while ((int)P < M) P <<= 1;

    for (unsigned k = 2; k <= P; k <<= 1) {
        for (unsigned j = k >> 1; j > 0; j >>= 1) {
            __syncthreads();
            for (unsigned i = tid; i < P; i += 1024) {
                unsigned ixj = i ^ j;
                if (ixj > i) {
                    unsigned long long a = sk[i], d = sk[ixj];
                    bool desc = ((i & k) == 0);
                    if (desc ? (a < d) : (a > d)) { sk[i] = d; sk[ixj] = a; }
                }
            }
        }
    }
    __syncthreads();
    for (int q = tid; q < MAXDET; q += 1024) {
        unsigned long long key = sk[q];
        unsigned sbits = (unsigned)(key >> 32);
        dscore[b * MAXDET + q] = __uint_as_float(sbits);
        didx[b * MAXDET + q]   = sbits ? (0xFFFFFFFFu - (unsigned)(key & 0xFFFFFFFFu)) : 0u;
    }
}

// wave per detection: gather row, first-occurrence argmax, box -> gbox/glabel
__global__ __launch_bounds__(512) void k_gather(const float* __restrict__ preds,
                                                const float* __restrict__ dscore,
                                                const unsigned* __restrict__ didx,
                                                float* __restrict__ gbox,
                                                int* __restrict__ glabel) {
    int g    = blockIdx.x * 8 + (threadIdx.x >> 6);   // b*MAXDET + k
    int lane = threadIdx.x & 63;
    float sc = dscore[g];
    if (sc > 0.f) {
        int b = g / MAXDET;
        int idx = (int)didx[g];
        const float* row = preds + ((size_t)b * NN + (size_t)idx) * NF;
        float v = row[5 + lane]; int ci = lane;
        if (lane < 16) { float v2 = row[69 + lane]; if (v2 > v) { v = v2; ci = lane + 64; } }
        #pragma unroll
        for (int m = 32; m >= 1; m >>= 1) {
            float ov = __shfl_xor(v, m);
            int   oi = __shfl_xor(ci, m);
            if (ov > v || (ov == v && oi < ci)) { v = ov; ci = oi; }
        }
        if (lane == 0) {
            float cx = row[0], cy = row[1], w = row[2], h = row[3];
            float x1 = cx - 0.5f * w, y1 = cy - 0.5f * h;   // 0.5*w exact -> fma-safe
            float4 bx = { x1, y1, x1 + w, y1 + h };
            ((float4*)gbox)[g] = bx;
            glabel[g] = ci;
        }
    } else if (lane == 0) {
        float4 zz = { 0.f, 0.f, 0.f, 0.f };
        ((float4*)gbox)[g] = zz;
        glabel[g] = -1;
    }
}

// one block per batch: boxes->LDS, suppression words into LDS (each written once,
// jw-rotated inner loop de-aliases stride-32 LDS reads), single-wave greedy, fused
// output write. IoU op-order matches reference; _rn blocks fma-contract.
__global__ __launch_bounds__(1024) void k_nms2(const float* __restrict__ gbox,
                                               const int* __restrict__ glabel,
                                               const float* __restrict__ dscore,
                                               float* __restrict__ out) {
    __shared__ float4   sbox[MAXDET];
    __shared__ int      slabel[MAXDET];
    __shared__ float    sscore[MAXDET];
    __shared__ unsigned supp[MAXDET * WORDS];
    int b = blockIdx.x;
    int tid = threadIdx.x;

    if (tid < MAXDET) {
        int g = b * MAXDET + tid;
        sbox[tid]   = ((const float4*)gbox)[g];
        slabel[tid] = glabel[g];
        sscore[tid] = dscore[g];
    }
    __syncthreads();

    // suppression bitmask: thread per 32-bit word, no atomics
    for (int T = tid; T < MAXDET * WORDS; T += 1024) {
        int i  = T / WORDS;
        int jw = T - i * WORDS;
        unsigned word = 0;
        int jbase = jw * 32;
        if (jbase + 31 > i) {
            float4 bi = sbox[i];
            int   li = slabel[i];
            float si = sscore[i];
            float ai = __fmul_rn(fmaxf(__fsub_rn(bi.z, bi.x), 0.f),
                                 fmaxf(__fsub_rn(bi.w, bi.y), 0.f));
            for (int tt = 0; tt < 32; ++tt) {
                int t = (tt + jw) & 31;       // rotation: neighbors hit different banks
                int j = jbase + t;
                if (j > i && j < MAXDET) {
                    if (slabel[j] == li && si > 0.f && sscore[j] > 0.f) {
                        float4 bj = sbox[j];
                        float xx1 = fmaxf(bi.x, bj.x);
                        float yy1 = fmaxf(bi.y, bj.y);
                        float xx2 = fminf(bi.z, bj.z);
                        float yy2 = fminf(bi.w, bj.w);
                        float iw = fmaxf(__fsub_rn(xx2, xx1), 0.f);
                        float ih = fmaxf(__fsub_rn(yy2, yy1), 0.f);
                        float inter = __fmul_rn(iw, ih);
                        float aj = __fmul_rn(fmaxf(__fsub_rn(bj.z, bj.x), 0.f),
                                             fmaxf(__fsub_rn(bj.w, bj.y), 0.f));
                        float den = __fadd_rn(__fsub_rn(__fadd_rn(ai, aj), inter), 1e-9f);
                        float iou = inter / den;     // exact IEEE div (no fast-math)
                        if (iou > NMSTH) word |= 1u << t;
                    }
                }
            }
        }
        supp[T] = word;
    }
    __syncthreads();

    // single-wave greedy: keep + nonzero-row summary in registers via ballot
    if (tid < 64) {
        int lane = tid;
        unsigned keep = 0, nzm = 0;
        #pragma unroll
        for (int s = 0; s < 5; ++s) {
            int k = s * 64 + lane;
            bool kb = (k < MAXDET) && (sscore[k] > 0.f);
            unsigned long long m = __ballot(kb);
            if (lane == 2 * s)     keep = (unsigned)m;
            if (lane == 2 * s + 1) keep = (unsigned)(m >> 32);
            unsigned nz = 0;
            if (k < MAXDET) {
                #pragma unroll
                for (int w = 0; w < WORDS; ++w) nz |= supp[k * WORDS + w];
            }
            unsigned long long mn = __ballot(nz != 0u);
            if (lane == 2 * s)     nzm = (unsigned)mn;
            if (lane == 2 * s + 1) nzm = (unsigned)(mn >> 32);
        }

        for (int i = 0; i < MAXDET; ++i) {
            int idx = i >> 5;                       // uniform
            unsigned kw = __shfl(keep, idx);
            unsigned nw = __shfl(nzm, idx);
            if (((kw & nw) >> (i & 31)) & 1u) {
                if (lane < WORDS) keep &= ~supp[i * WORDS + lane];
            }
        }

        #pragma unroll
        for (int s = 0; s < 5; ++s) {
            int k = s * 64 + lane;
            if (k < MAXDET) {
                unsigned kw = __shfl(keep, k >> 5);
                bool kp = (kw >> (k & 31)) & 1u;
                int g = b * MAXDET + k;
                float4 bx = sbox[k];
                float4 zz = { 0.f, 0.f, 0.f, 0.f };
                ((float4*)(out + O_PB))[g] = kp ? bx : zz;
                out[O_PS + g] = kp ? sscore[k] : 0.f;
                out[O_PL + g] = kp ? (float)slabel[k] : -1.f;
                out[O_PV + g] = kp ? 1.f : 0.f;
            }
        }
    }
}

extern "C" void kernel_launch(void* const* d_in, const int* in_sizes, int n_in,
                              void* d_out, int out_size, void* d_ws, size_t ws_size,
                              hipStream_t stream) {
    const float* preds = (const float*)d_in[0];
    const float* tt    = (const float*)d_in[1];
    const int*   len   = (const int*)d_in[2];
    float* out = (float*)d_out;

    char* ws = (char*)d_ws;
    float*    scores = (float*)(ws + WS_SCORE);
    float*    dscore = (float*)(ws + WS_DS);
    unsigned* didx   = (unsigned*)(ws + WS_DI);
    float*    gbox   = (float*)(ws + WS_GBOX);
    int*      glabel = (int*)(ws + WS_GLAB);

    k_score <<<PBLK, 256, 0, stream>>>(preds, scores, tt, len, out);
    k_select<<<BB, 1024, 0, stream>>>(scores, dscore, didx);
    k_gather<<<(BB * MAXDET) / 8, 512, 0, stream>>>(preds, dscore, didx, gbox, glabel);
    k_nms2  <<<BB, 1024, 0, stream>>>(gbox, glabel, dscore, out);
}

// Round 8
// 111.201 us; speedup vs baseline: 1.1218x; 1.1218x over previous
//
#include <hip/hip_runtime.h>
#include <cstdint>

#define BB 16
#define NN 25200
#define NCLS 80
#define NF (5 + NCLS)
#define MAXDET 300
#define MTGT 50
#define CONF 0.8f
#define NMSTH 0.4f
#define WORDS 10
#define NBINS 2048
#define SBUF 2048
#define APB 64                              // anchors per block in k_score
#define CHUNK_V4 (APB * NF / 4)             // 1360 float4 per block
#define SCORE_BLOCKS ((BB * NN) / APB)      // 6300
#define NTGT_BLOCKS ((BB * MTGT + 127) / 128)

// workspace byte offsets
#define WS_SCORE 0

// output float offsets (return order: pb, ps, pl, pv, tb, ts, tl, tv)
#define O_PB 0
#define O_PS (BB * MAXDET * 4)
#define O_PL (O_PS + BB * MAXDET)
#define O_PV (O_PL + BB * MAXDET)
#define O_TB (O_PV + BB * MAXDET)
#define O_TS (O_TB + BB * MTGT * 4)
#define O_TL (O_TS + BB * MTGT)
#define O_TV (O_TL + BB * MTGT)

// 128-thread block stages 64 rows (21.76 KB -> 7 blocks/CU) via async
// global_load_lds width=16 (no VGPR round-trip: 11 loads in flight per wave,
// wave parks at barrier). Scan: 2 threads/anchor (banks 21a+8h mod 32 = exact
// 2-way = free), 4 max accumulators (max is order-independent -> bit-exact),
// one shfl_xor, single f32 mul. Tail blocks do the target transform.
__global__ __launch_bounds__(128) void k_score(const float* __restrict__ preds,
                                               float* __restrict__ scores,
                                               const float* __restrict__ tt,
                                               const int* __restrict__ len,
                                               float* __restrict__ out) {
    __shared__ float st[APB * NF];          // 21760 B
    int tid = threadIdx.x;
    int bid = blockIdx.x;

    if (bid >= SCORE_BLOCKS) {              // fused target transform
        int t = (bid - SCORE_BLOCKS) * 128 + tid;
        if (t < BB * MTGT) {
            int b = t / MTGT, m = t - b * MTGT;
            const float* row = tt + (size_t)t * 6;
            bool valid = m < len[b];
            float cx = row[0], cy = row[1], w = row[2], h = row[3];
            float x1 = cx - 0.5f * w, y1 = cy - 0.5f * h;
            float* tb = out + O_TB + (size_t)t * 4;
            tb[0] = valid ? x1 : 0.f;
            tb[1] = valid ? y1 : 0.f;
            tb[2] = valid ? (x1 + w) : 0.f;
            tb[3] = valid ? (y1 + h) : 0.f;
            out[O_TS + t] = valid ? row[4] : 0.f;
            out[O_TL + t] = valid ? (float)(int)row[5] : -1.f;
            out[O_TV + t] = valid ? 1.f : 0.f;
        }
        return;
    }

    int w = tid >> 6;                       // wave id (uniform per wave)
    const float4* src = (const float4*)(preds + (size_t)bid * (APB * NF));
    #pragma unroll
    for (int i = 0; i < 11; ++i) {
        int idx = i * 128 + tid;            // global float4 index, contiguous
        if (idx < CHUNK_V4) {
            // LDS dest: wave-uniform base; HW scatters lane l at base + l*16.
            __builtin_amdgcn_global_load_lds(
                (const __attribute__((address_space(1))) void*)(src + idx),
                (__attribute__((address_space(3))) void*)(st + (i * 128 + w * 64) * 4),
                16, 0, 0);
        }
    }
    __syncthreads();                        // drains vmcnt -> LDS valid

    int a = tid >> 1, h = tid & 1;          // anchor, half
    const float* cls = st + a * NF + 5 + h * 40;
    float m0 = cls[0], m1 = cls[1], m2 = cls[2], m3 = cls[3];
    #pragma unroll
    for (int f = 4; f < 40; f += 4) {
        m0 = fmaxf(m0, cls[f]);     m1 = fmaxf(m1, cls[f + 1]);
        m2 = fmaxf(m2, cls[f + 2]); m3 = fmaxf(m3, cls[f + 3]);
    }
    float m = fmaxf(fmaxf(m0, m1), fmaxf(m2, m3));
    m = fmaxf(m, __shfl_xor(m, 1));
    if (h == 0) scores[bid * APB + a] = st[a * NF + 4] * m;  // single mul, bit-exact
}

// One block per batch: histogram select + exact bitonic sort of survivors +
// top-300 gather/argmax + suppression matrix + single-wave greedy + output.
// Coarse bins only SELECT (cut-bin ties all included); 64-bit key sort ORDERS
// -> bit-identical to full sort (JAX top_k tie semantics via inverted index).
__global__ __launch_bounds__(1024) void k_post(const float* __restrict__ scores,
                                               const float* __restrict__ preds,
                                               float* __restrict__ out) {
    __shared__ int hist[NBINS];
    __shared__ unsigned long long sk[SBUF];
    __shared__ float4   sbox[MAXDET];
    __shared__ int      slabel[MAXDET];
    __shared__ float    sscore[MAXDET];
    __shared__ unsigned supp[MAXDET * WORDS];
    __shared__ int lcnt;
    __shared__ int scut;
    int b = blockIdx.x;
    int tid = threadIdx.x;
    int lane = tid & 63;

    if (tid == 0) lcnt = 0;
    for (int i = tid; i < NBINS; i += 1024) hist[i] = 0;
    for (int i = tid; i < SBUF; i += 1024) sk[i] = 0ull;
    __syncthreads();

    // phase A: histogram of candidate score bits. scores in (0.8,1.0] share one
    // exponent region -> (u - 0x3F400000)>>12 is monotone in float order.
    for (int i = tid; i < NN; i += 1024) {
        float s = scores[b * NN + i];
        if (s > CONF) {
            unsigned u = __float_as_uint(s);
            int bin = (int)((u - 0x3F400000u) >> 12);
            bin = bin < 0 ? 0 : (bin > NBINS - 1 ? NBINS - 1 : bin);
            atomicAdd(&hist[bin], 1);
        }
    }
    __syncthreads();

    // phase B: find cut bin (largest bin with suffix-count >= 300), one wave
    if (tid < 64) {
        int sb = 0;
        #pragma unroll
        for (int k = 0; k < 32; ++k) sb += hist[tid * 32 + k];
        int cum = sb;                              // suffix sum over 64 superbins
        #pragma unroll
        for (int d = 1; d < 64; d <<= 1) {
            int o = __shfl_down(cum, d);
            if (lane + d < 64) cum += o;
        }
        unsigned long long m = __ballot(cum >= MAXDET);
        int cutbin = 0;
        if (m) {
            int cutS = 63 - __clzll(m);
            int tail = (cutS < 63) ? __shfl(cum, cutS + 1) : 0;
            int hh = (lane < 32) ? hist[cutS * 32 + lane] : 0;
            int c2 = hh;                           // suffix sum within superbin
            #pragma unroll
            for (int d = 1; d < 32; d <<= 1) {
                int o = __shfl_down(c2, d);
                if (lane + d < 32) c2 += o;
            }
            c2 += tail;
            unsigned long long m2 = __ballot(lane < 32 && c2 >= MAXDET);
            int cutL = 63 - __clzll(m2);           // m2 != 0 guaranteed
            cutbin = cutS * 32 + cutL;
        }
        if (lane == 0) scut = cutbin;
    }
    __syncthreads();
    int cutbin = scut;

    // phase C: compact bin >= cutbin (wave-aggregated LDS atomic)
    for (int i = tid; i < ((NN + 1023) & ~1023); i += 1024) {
        float s = 0.f; bool pass = false;
        if (i < NN) {
            s = scores[b * NN + i];
            if (s > CONF) {
                unsigned u = __float_as_uint(s);
                int bin = (int)((u - 0x3F400000u) >> 12);
                bin = bin < 0 ? 0 : (bin > NBINS - 1 ? NBINS - 1 : bin);
                pass = bin >= cutbin;
            }
        }
        unsigned long long mask = __ballot(pass);
        int wcnt = __popcll(mask);
        int bs = 0;
        if (lane == 0 && wcnt) bs = atomicAdd(&lcnt, wcnt);
        bs = __shfl(bs, 0);
        if (pass) {
            int pos = bs + __popcll(mask & ((1ull << lane) - 1ull));
            if (pos < SBUF)
                sk[pos] = ((unsigned long long)__float_as_uint(s) << 32) |
                          (unsigned long long)(0xFFFFFFFFu - (unsigned)i);
        }
    }
    __syncthreads();

    // phase D: bitonic sort P in {512,1024,2048} elements, descending
    int M = lcnt; if (M > SBUF) M = SBUF;
    unsigned P = 512;
    while ((int)P < M) P <<= 1;

    for (unsigned k = 2; k <= P; k <<= 1) {
        for (unsigned j = k >> 1; j > 0; j >>= 1) {
            __syncthreads();
            for (unsigned i = tid; i < P; i += 1024) {
                unsigned ixj = i ^ j;
                if (ixj > i) {
                    unsigned long long a = sk[i], d = sk[ixj];
                    bool desc = ((i & k) == 0);
                    if (desc ? (a < d) : (a > d)) { sk[i] = d; sk[ixj] = a; }
                }
            }
        }
    }
    __syncthreads();

    // phase E: gather top-300 rows, wave per detection, first-occurrence argmax
    {
        int wv = tid >> 6;
        for (int k = wv; k < MAXDET; k += 16) {
            unsigned long long key = sk[k];
            unsigned sbits = (unsigned)(key >> 32);
            if (sbits) {
                int idx = (int)(0xFFFFFFFFu - (unsigned)(key & 0xFFFFFFFFu));
                const float* row = preds + ((size_t)b * NN + (size_t)idx) * NF;
                float v = row[5 + lane]; int ci = lane;
                if (lane < 16) { float v2 = row[69 + lane]; if (v2 > v) { v = v2; ci = lane + 64; } }
                #pragma unroll
                for (int m = 32; m >= 1; m >>= 1) {
                    float ov = __shfl_xor(v, m);
                    int   oi = __shfl_xor(ci, m);
                    if (ov > v || (ov == v && oi < ci)) { v = ov; ci = oi; }
                }
                if (lane == 0) {
                    float cx = row[0], cy = row[1], w = row[2], h = row[3];
                    float x1 = cx - 0.5f * w, y1 = cy - 0.5f * h;   // fma-safe
                    float4 bx = { x1, y1, x1 + w, y1 + h };
                    sbox[k] = bx;
                    slabel[k] = ci;
                    sscore[k] = __uint_as_float(sbits);
                }
            } else if (lane == 0) {
                float4 zz = { 0.f, 0.f, 0.f, 0.f };
                sbox[k] = zz; slabel[k] = -1; sscore[k] = 0.f;
            }
        }
    }
    __syncthreads();

    // phase F: suppression bitmask, thread per 32-bit word, no atomics.
    // IoU op-order matches reference; _rn blocks fma-contract.
    for (int T = tid; T < MAXDET * WORDS; T += 1024) {
        int i  = T / WORDS;
        int jw = T - i * WORDS;
        unsigned word = 0;
        int jbase = jw * 32;
        if (jbase + 31 > i) {
            float4 bi = sbox[i];
            int   li = slabel[i];
            float si = sscore[i];
            float ai = __fmul_rn(fmaxf(__fsub_rn(bi.z, bi.x), 0.f),
                                 fmaxf(__fsub_rn(bi.w, bi.y), 0.f));
            for (int uu = 0; uu < 32; ++uu) {
                int t = (uu + jw) & 31;       // rotation de-aliases LDS banks
                int j = jbase + t;
                if (j > i && j < MAXDET) {
                    if (slabel[j] == li && si > 0.f && sscore[j] > 0.f) {
                        float4 bj = sbox[j];
                        float xx1 = fmaxf(bi.x, bj.x);
                        float yy1 = fmaxf(bi.y, bj.y);
                        float xx2 = fminf(bi.z, bj.z);
                        float yy2 = fminf(bi.w, bj.w);
                        float iw = fmaxf(__fsub_rn(xx2, xx1), 0.f);
                        float ih = fmaxf(__fsub_rn(yy2, yy1), 0.f);
                        float inter = __fmul_rn(iw, ih);
                        float aj = __fmul_rn(fmaxf(__fsub_rn(bj.z, bj.x), 0.f),
                                             fmaxf(__fsub_rn(bj.w, bj.y), 0.f));
                        float den = __fadd_rn(__fsub_rn(__fadd_rn(ai, aj), inter), 1e-9f);
                        float iou = inter / den;     // exact IEEE div
                        if (iou > NMSTH) word |= 1u << t;
                    }
                }
            }
        }
        supp[T] = word;
    }
    __syncthreads();

    // phase G: single-wave greedy (keep + nonzero-row summary in registers via
    // ballot; LDS touched only on actual suppressions) + fused output write.
    if (tid < 64) {
        unsigned keep = 0, nzm = 0;
        #pragma unroll
        for (int s = 0; s < 5; ++s) {
            int k = s * 64 + lane;
            bool kb = (k < MAXDET) && (sscore[k] > 0.f);
            unsigned long long m = __ballot(kb);
            if (lane == 2 * s)     keep = (unsigned)m;
            if (lane == 2 * s + 1) keep = (unsigned)(m >> 32);
            unsigned nz = 0;
            if (k < MAXDET) {
                #pragma unroll
                for (int w = 0; w < WORDS; ++w) nz |= supp[k * WORDS + w];
            }
            unsigned long long mn = __ballot(nz != 0u);
            if (lane == 2 * s)     nzm = (unsigned)mn;
            if (lane == 2 * s + 1) nzm = (unsigned)(mn >> 32);
        }

        for (int i = 0; i < MAXDET; ++i) {
            int idx = i >> 5;                       // uniform
            unsigned kw = __shfl(keep, idx);
            unsigned nw = __shfl(nzm, idx);
            if (((kw & nw) >> (i & 31)) & 1u) {
                if (lane < WORDS) keep &= ~supp[i * WORDS + lane];
            }
        }

        #pragma unroll
        for (int s = 0; s < 5; ++s) {
            int k = s * 64 + lane;
            if (k < MAXDET) {
                unsigned kw = __shfl(keep, k >> 5);
                bool kp = (kw >> (k & 31)) & 1u;
                int g = b * MAXDET + k;
                float4 bx = sbox[k];
                float4 zz = { 0.f, 0.f, 0.f, 0.f };
                ((float4*)(out + O_PB))[g] = kp ? bx : zz;
                out[O_PS + g] = kp ? sscore[k] : 0.f;
                out[O_PL + g] = kp ? (float)slabel[k] : -1.f;
                out[O_PV + g] = kp ? 1.f : 0.f;
            }
        }
    }
}

extern "C" void kernel_launch(void* const* d_in, const int* in_sizes, int n_in,
                              void* d_out, int out_size, void* d_ws, size_t ws_size,
                              hipStream_t stream) {
    const float* preds = (const float*)d_in[0];
    const float* tt    = (const float*)d_in[1];
    const int*   len   = (const int*)d_in[2];
    float* out = (float*)d_out;

    float* scores = (float*)((char*)d_ws + WS_SCORE);

    k_score<<<SCORE_BLOCKS + NTGT_BLOCKS, 128, 0, stream>>>(preds, scores, tt, len, out);
    k_post <<<BB, 1024, 0, stream>>>(scores, preds, out);
}

// Round 9
// 96.547 us; speedup vs baseline: 1.2921x; 1.1518x over previous
//
#include <hip/hip_runtime.h>
#include <cstdint>

#define BB 16
#define NN 25200
#define NCLS 80
#define NF (5 + NCLS)
#define MAXDET 300
#define MTGT 50
#define CONF 0.8f
#define NMSTH 0.4f
#define WORDS 10
#define NBINS 2048
#define SBUF 2048
#define APB 64                              // anchors per block in k_score
#define CHUNK_V4 (APB * NF / 4)             // 1360 float4 per block
#define SCORE_BLOCKS ((BB * NN) / APB)      // 6300
#define NTGT_BLOCKS ((BB * MTGT + 127) / 128)
#define HSTRIDE 33                          // hist row stride (bank de-alias)

// workspace byte offsets
#define WS_SCORE 0
#define WS_DS   ((size_t)BB * NN * 4)
#define WS_DI   (WS_DS + (size_t)BB * MAXDET * 4)
#define WS_GBOX (WS_DI + (size_t)BB * MAXDET * 4)
#define WS_GLAB (WS_GBOX + (size_t)BB * MAXDET * 16)
#define WS_SUPP (WS_GLAB + (size_t)BB * MAXDET * 4)

// output float offsets (return order: pb, ps, pl, pv, tb, ts, tl, tv)
#define O_PB 0
#define O_PS (BB * MAXDET * 4)
#define O_PL (O_PS + BB * MAXDET)
#define O_PV (O_PL + BB * MAXDET)
#define O_TB (O_PV + BB * MAXDET)
#define O_TS (O_TB + BB * MTGT * 4)
#define O_TL (O_TS + BB * MTGT)
#define O_TV (O_TL + BB * MTGT)

// 128-thread block stages 64 rows (21.76 KB -> 7 blocks/CU) via async
// global_load_lds width=16 (no VGPR round-trip). Scan: 2 threads/anchor
// (banks 21a+8h mod 32 = exact 2-way = free), 4 max accumulators (max is
// order-independent -> bit-exact), one shfl_xor, single f32 mul.
// Tail blocks do the target transform.
__global__ __launch_bounds__(128) void k_score(const float* __restrict__ preds,
                                               float* __restrict__ scores,
                                               const float* __restrict__ tt,
                                               const int* __restrict__ len,
                                               float* __restrict__ out) {
    __shared__ float st[APB * NF];          // 21760 B
    int tid = threadIdx.x;
    int bid = blockIdx.x;

    if (bid >= SCORE_BLOCKS) {              // fused target transform
        int t = (bid - SCORE_BLOCKS) * 128 + tid;
        if (t < BB * MTGT) {
            int b = t / MTGT, m = t - b * MTGT;
            const float* row = tt + (size_t)t * 6;
            bool valid = m < len[b];
            float cx = row[0], cy = row[1], w = row[2], h = row[3];
            float x1 = cx - 0.5f * w, y1 = cy - 0.5f * h;
            float* tb = out + O_TB + (size_t)t * 4;
            tb[0] = valid ? x1 : 0.f;
            tb[1] = valid ? y1 : 0.f;
            tb[2] = valid ? (x1 + w) : 0.f;
            tb[3] = valid ? (y1 + h) : 0.f;
            out[O_TS + t] = valid ? row[4] : 0.f;
            out[O_TL + t] = valid ? (float)(int)row[5] : -1.f;
            out[O_TV + t] = valid ? 1.f : 0.f;
        }
        return;
    }

    int w = tid >> 6;                       // wave id (uniform per wave)
    const float4* src = (const float4*)(preds + (size_t)bid * (APB * NF));
    #pragma unroll
    for (int i = 0; i < 11; ++i) {
        int idx = i * 128 + tid;            // global float4 index, contiguous
        if (idx < CHUNK_V4) {
            // LDS dest: wave-uniform base; HW scatters lane l at base + l*16.
            __builtin_amdgcn_global_load_lds(
                (const __attribute__((address_space(1))) void*)(src + idx),
                (__attribute__((address_space(3))) void*)(st + (i * 128 + w * 64) * 4),
                16, 0, 0);
        }
    }
    __syncthreads();                        // drains vmcnt -> LDS valid

    int a = tid >> 1, h = tid & 1;          // anchor, half
    const float* cls = st + a * NF + 5 + h * 40;
    float m0 = cls[0], m1 = cls[1], m2 = cls[2], m3 = cls[3];
    #pragma unroll
    for (int f = 4; f < 40; f += 4) {
        m0 = fmaxf(m0, cls[f]);     m1 = fmaxf(m1, cls[f + 1]);
        m2 = fmaxf(m2, cls[f + 2]); m3 = fmaxf(m3, cls[f + 3]);
    }
    float m = fmaxf(fmaxf(m0, m1), fmaxf(m2, m3));
    m = fmaxf(m, __shfl_xor(m, 1));
    if (h == 0) scores[bid * APB + a] = st[a * NF + 4] * m;  // single mul, bit-exact
}

// One block per batch: histogram select + rank-by-counting (NO bitonic sort).
// Coarse bins only SELECT (cut-bin ties all included); exact 64-bit key rank
// ORDERS -> bit-identical to a full sort (JAX top_k ties via inverted index).
__global__ __launch_bounds__(1024) void k_select(const float* __restrict__ scores,
                                                 float* __restrict__ dscore,
                                                 unsigned* __restrict__ didx) {
    __shared__ int hist[64 * HSTRIDE];      // superbin-major, stride 33: bank-clean
    __shared__ unsigned long long sk[SBUF];
    __shared__ int lcnt;
    __shared__ int scut;
    int b = blockIdx.x;
    int tid = threadIdx.x;
    int lane = tid & 63;

    if (tid == 0) lcnt = 0;
    for (int i = tid; i < 64 * HSTRIDE; i += 1024) hist[i] = 0;
    if (tid < MAXDET) {                     // zero-prefill outputs (M<300 tail)
        dscore[b * MAXDET + tid] = 0.f;
        didx[b * MAXDET + tid] = 0u;
    }
    __syncthreads();

    // phase A: histogram of candidate score bits. scores in (0.8,1.0] share one
    // exponent region -> (u - 0x3F400000)>>12 is monotone in float order.
    for (int i = tid; i < NN; i += 1024) {
        float s = scores[b * NN + i];
        if (s > CONF) {
            unsigned u = __float_as_uint(s);
            int bin = (int)((u - 0x3F400000u) >> 12);
            bin = bin < 0 ? 0 : (bin > NBINS - 1 ? NBINS - 1 : bin);
            atomicAdd(&hist[(bin >> 5) * HSTRIDE + (bin & 31)], 1);
        }
    }
    __syncthreads();

    // phase B: find cut bin (largest bin with suffix-count >= 300), one wave
    if (tid < 64) {
        int sb = 0;
        #pragma unroll
        for (int k = 0; k < 32; ++k) sb += hist[lane * HSTRIDE + k];  // banks (lane+k)%32: clean
        int cum = sb;                              // suffix sum over 64 superbins
        #pragma unroll
        for (int d = 1; d < 64; d <<= 1) {
            int o = __shfl_down(cum, d);
            if (lane + d < 64) cum += o;
        }
        unsigned long long m = __ballot(cum >= MAXDET);
        int cutbin = 0;
        if (m) {
            int cutS = 63 - __clzll(m);
            int tail = (cutS < 63) ? __shfl(cum, cutS + 1) : 0;
            int hh = (lane < 32) ? hist[cutS * HSTRIDE + lane] : 0;
            int c2 = hh;                           // suffix sum within superbin
            #pragma unroll
            for (int d = 1; d < 32; d <<= 1) {
                int o = __shfl_down(c2, d);
                if (lane + d < 32) c2 += o;
            }
            c2 += tail;
            unsigned long long m2 = __ballot(lane < 32 && c2 >= MAXDET);
            int cutL = 63 - __clzll(m2);           // m2 != 0 guaranteed
            cutbin = cutS * 32 + cutL;
        }
        if (lane == 0) scut = cutbin;
    }
    __syncthreads();
    int cutbin = scut;

    // phase C: compact bin >= cutbin (wave-aggregated LDS atomic)
    for (int i = tid; i < ((NN + 1023) & ~1023); i += 1024) {
        float s = 0.f; bool pass = false;
        if (i < NN) {
            s = scores[b * NN + i];
            if (s > CONF) {
                unsigned u = __float_as_uint(s);
                int bin = (int)((u - 0x3F400000u) >> 12);
                bin = bin < 0 ? 0 : (bin > NBINS - 1 ? NBINS - 1 : bin);
                pass = bin >= cutbin;
            }
        }
        unsigned long long mask = __ballot(pass);
        int wcnt = __popcll(mask);
        int bs = 0;
        if (lane == 0 && wcnt) bs = atomicAdd(&lcnt, wcnt);
        bs = __shfl(bs, 0);
        if (pass) {
            int pos = bs + __popcll(mask & ((1ull << lane) - 1ull));
            if (pos < SBUF)
                sk[pos] = ((unsigned long long)__float_as_uint(s) << 32) |
                          (unsigned long long)(0xFFFFFFFFu - (unsigned)i);
        }
    }
    __syncthreads();

    // phase D: rank-by-counting. Keys all distinct (index in low bits) -> ranks
    // are an exact permutation; rank r == position in the descending full sort.
    // Inner reads are same-address LDS broadcasts (conflict-free), no barriers.
    int M = lcnt; if (M > SBUF) M = SBUF;
    for (int c = tid; c < M; c += 1024) {
        unsigned long long key = sk[c];
        int rank = 0;
        for (int j = 0; j < M; ++j) rank += (sk[j] > key) ? 1 : 0;
        if (rank < MAXDET) {
            dscore[b * MAXDET + rank] = __uint_as_float((unsigned)(key >> 32));
            didx[b * MAXDET + rank]   = 0xFFFFFFFFu - (unsigned)(key & 0xFFFFFFFFu);
        }
    }
}

// wave per detection: gather row, first-occurrence argmax, box -> gbox/glabel
__global__ __launch_bounds__(512) void k_gather(const float* __restrict__ preds,
                                                const float* __restrict__ dscore,
                                                const unsigned* __restrict__ didx,
                                                float* __restrict__ gbox,
                                                int* __restrict__ glabel) {
    int g    = blockIdx.x * 8 + (threadIdx.x >> 6);   // b*MAXDET + k
    int lane = threadIdx.x & 63;
    float sc = dscore[g];
    if (sc > 0.f) {
        int b = g / MAXDET;
        int idx = (int)didx[g];
        const float* row = preds + ((size_t)b * NN + (size_t)idx) * NF;
        float v = row[5 + lane]; int ci = lane;
        if (lane < 16) { float v2 = row[69 + lane]; if (v2 > v) { v = v2; ci = lane + 64; } }
        #pragma unroll
        for (int m = 32; m >= 1; m >>= 1) {
            float ov = __shfl_xor(v, m);
            int   oi = __shfl_xor(ci, m);
            if (ov > v || (ov == v && oi < ci)) { v = ov; ci = oi; }
        }
        if (lane == 0) {
            float cx = row[0], cy = row[1], w = row[2], h = row[3];
            float x1 = cx - 0.5f * w, y1 = cy - 0.5f * h;   // 0.5*w exact -> fma-safe
            float4 bx = { x1, y1, x1 + w, y1 + h };
            ((float4*)gbox)[g] = bx;
            glabel[g] = ci;
        }
    } else if (lane == 0) {
        float4 zz = { 0.f, 0.f, 0.f, 0.f };
        ((float4*)gbox)[g] = zz;
        glabel[g] = -1;
    }
}

// thread per 32-bit suppression word: 32 serial IoUs, no atomics, each word
// written once. IoU op-order matches reference; _rn blocks fma-contract.
__global__ __launch_bounds__(256) void k_mask(const float* __restrict__ gbox,
                                              const int* __restrict__ glabel,
                                              const float* __restrict__ dscore,
                                              unsigned* __restrict__ gsupp) {
    int T = blockIdx.x * 256 + threadIdx.x;
    if (T >= BB * MAXDET * WORDS) return;
    int g  = T / WORDS;                    // b*MAXDET + i
    int jw = T - g * WORDS;
    int b  = g / MAXDET;
    int i  = g - b * MAXDET;

    unsigned word = 0;
    int jbase = jw * 32;
    if (jbase + 31 > i) {                  // word has some j > i
        float4 bi = ((const float4*)gbox)[g];
        int   li = glabel[g];
        float si = dscore[g];
        float ai = __fmul_rn(fmaxf(__fsub_rn(bi.z, bi.x), 0.f),
                             fmaxf(__fsub_rn(bi.w, bi.y), 0.f));
        #pragma unroll 4
        for (int t = 0; t < 32; ++t) {
            int j = jbase + t;
            if (j > i && j < MAXDET) {
                int gj = b * MAXDET + j;
                if (glabel[gj] == li && si > 0.f && dscore[gj] > 0.f) {
                    float4 bj = ((const float4*)gbox)[gj];
                    float xx1 = fmaxf(bi.x, bj.x);
                    float yy1 = fmaxf(bi.y, bj.y);
                    float xx2 = fminf(bi.z, bj.z);
                    float yy2 = fminf(bi.w, bj.w);
                    float iw = fmaxf(__fsub_rn(xx2, xx1), 0.f);
                    float ih = fmaxf(__fsub_rn(yy2, yy1), 0.f);
                    float inter = __fmul_rn(iw, ih);
                    float aj = __fmul_rn(fmaxf(__fsub_rn(bj.z, bj.x), 0.f),
                                         fmaxf(__fsub_rn(bj.w, bj.y), 0.f));
                    float den = __fadd_rn(__fsub_rn(__fadd_rn(ai, aj), inter), 1e-9f);
                    float iou = inter / den;     // exact IEEE div (no fast-math)
                    if (iou > NMSTH) word |= 1u << t;
                }
            }
        }
    }
    gsupp[T] = word;
}

// one wave per batch: register-resident keep + nonzero-row summary; LDS touched
// only on actual suppressions. Fused output write (single wave -> no syncs).
__global__ __launch_bounds__(64) void k_greedy(const float* __restrict__ gbox,
                                               const int* __restrict__ glabel,
                                               const float* __restrict__ dscore,
                                               const unsigned* __restrict__ gsupp,
                                               float* __restrict__ out) {
    __shared__ unsigned ls[MAXDET * WORDS];
    int b = blockIdx.x;
    int lane = threadIdx.x;

    for (int w = lane; w < MAXDET * WORDS; w += 64)
        ls[w] = gsupp[b * MAXDET * WORDS + w];
    __syncthreads();

    unsigned keep = 0, nzm = 0;
    #pragma unroll
    for (int s = 0; s < 5; ++s) {
        int k = s * 64 + lane;
        bool kb = (k < MAXDET) && (dscore[b * MAXDET + k] > 0.f);
        unsigned long long m = __ballot(kb);
        if (lane == 2 * s)     keep = (unsigned)m;
        if (lane == 2 * s + 1) keep = (unsigned)(m >> 32);
        unsigned nz = 0;
        if (k < MAXDET) {
            #pragma unroll
            for (int w = 0; w < WORDS; ++w) nz |= ls[k * WORDS + w];
        }
        unsigned long long mn = __ballot(nz != 0u);
        if (lane == 2 * s)     nzm = (unsigned)mn;
        if (lane == 2 * s + 1) nzm = (unsigned)(mn >> 32);
    }

    for (int i = 0; i < MAXDET; ++i) {
        int idx = i >> 5;                       // uniform
        unsigned kw = __shfl(keep, idx);
        unsigned nw = __shfl(nzm, idx);
        if (((kw & nw) >> (i & 31)) & 1u) {
            if (lane < WORDS) keep &= ~ls[i * WORDS + lane];
        }
    }

    #pragma unroll
    for (int s = 0; s < 5; ++s) {
        int k = s * 64 + lane;
        if (k < MAXDET) {
            unsigned kw = __shfl(keep, k >> 5);
            bool kp = (kw >> (k & 31)) & 1u;
            int g = b * MAXDET + k;
            float4 bx = ((const float4*)gbox)[g];
            float4 zz = { 0.f, 0.f, 0.f, 0.f };
            ((float4*)(out + O_PB))[g] = kp ? bx : zz;
            out[O_PS + g] = kp ? dscore[g] : 0.f;
            out[O_PL + g] = kp ? (float)glabel[g] : -1.f;
            out[O_PV + g] = kp ? 1.f : 0.f;
        }
    }
}

extern "C" void kernel_launch(void* const* d_in, const int* in_sizes, int n_in,
                              void* d_out, int out_size, void* d_ws, size_t ws_size,
                              hipStream_t stream) {
    const float* preds = (const float*)d_in[0];
    const float* tt    = (const float*)d_in[1];
    const int*   len   = (const int*)d_in[2];
    float* out = (float*)d_out;

    char* ws = (char*)d_ws;
    float*    scores = (float*)(ws + WS_SCORE);
    float*    dscore = (float*)(ws + WS_DS);
    unsigned* didx   = (unsigned*)(ws + WS_DI);
    float*    gbox   = (float*)(ws + WS_GBOX);
    int*      glabel = (int*)(ws + WS_GLAB);
    unsigned* gsupp  = (unsigned*)(ws + WS_SUPP);

    k_score <<<SCORE_BLOCKS + NTGT_BLOCKS, 128, 0, stream>>>(preds, scores, tt, len, out);
    k_select<<<BB, 1024, 0, stream>>>(scores, dscore, didx);
    k_gather<<<(BB * MAXDET) / 8, 512, 0, stream>>>(preds, dscore, didx, gbox, glabel);
    k_mask  <<<(BB * MAXDET * WORDS + 255) / 256, 256, 0, stream>>>(gbox, glabel, dscore, gsupp);
    k_greedy<<<BB, 64, 0, stream>>>(gbox, glabel, dscore, gsupp, out);
}